// Round 4
// baseline (396.515 us; speedup 1.0000x reference)
//
#include <hip/hip_runtime.h>

// N=50000, E=400000, D=128, DE=64, H=8
#define D 128
#define DE 64
#define SLOPE 0.2f
#define EPS 1e-5f

typedef float f32x4 __attribute__((ext_vector_type(4)));
typedef short bf16x8 __attribute__((ext_vector_type(8)));
typedef unsigned short ushort;

__device__ __forceinline__ float lrelu(float x) { return x > 0.f ? x : SLOPE * x; }

// fp32 -> bf16 RNE
__device__ __forceinline__ ushort f2bf(float x) {
  union { float f; unsigned u; } c; c.f = x;
  unsigned r = c.u + 0x7FFFu + ((c.u >> 16) & 1u);
  return (ushort)(r >> 16);
}
__device__ __forceinline__ float bf2f(unsigned u) {
  return __uint_as_float(u << 16);
}
__device__ __forceinline__ uint4 cvt8(const float* p) {
  float4 f0 = *(const float4*)p;
  float4 f1 = *(const float4*)(p + 4);
  union { ushort us[8]; uint4 v; } u;
  u.us[0] = f2bf(f0.x); u.us[1] = f2bf(f0.y);
  u.us[2] = f2bf(f0.z); u.us[3] = f2bf(f0.w);
  u.us[4] = f2bf(f1.x); u.us[5] = f2bf(f1.y);
  u.us[6] = f2bf(f1.z); u.us[7] = f2bf(f1.w);
  return u.v;
}

// ---------------------------------------------------------------------------
// K0: fold weights + pack bf16 tables + deg histogram (blocks >= 577).
// WnP/WvP/AfqP/AfkP are emitted in MFMA B-FRAGMENT order so node_gemm reads
// them directly from global (L2-resident 32KB tables), no LDS staging:
//   element (outcol, k) -> idx = (((ch*8+nt)*4+quad)*16+l15)*8+jj
//   where nt=outcol>>4, l15=outcol&15, ch=k>>5, quad=(k>>3)&3, jj=k&7.
// AfeT keeps the old [outcol][k] layout (consumed by edge_fused4's LDS path).
__global__ __launch_bounds__(128) void fold_pack(
    const float* __restrict__ Wq, const float* __restrict__ Wk,
    const float* __restrict__ We, const float* __restrict__ A1,
    const float* __restrict__ bq, const float* __restrict__ bk,
    const float* __restrict__ be, const float* __restrict__ b1,
    const float* __restrict__ Wn, const float* __restrict__ Wv,
    ushort* __restrict__ AfqP, ushort* __restrict__ AfkP,
    ushort* __restrict__ AfeT, float* __restrict__ bfold,
    ushort* __restrict__ WnP, ushort* __restrict__ WvP,
    const int* __restrict__ src, int* __restrict__ deg, int E) {
  int r = blockIdx.x;
  int j = threadIdx.x;
  if (r < 128) {
    // F_q[k=r][outcol=j]
    float acc = 0.f;
    for (int t = 0; t < 128; ++t) acc += Wq[r * 128 + t] * A1[t * 128 + j];
    int ch = r >> 5, quad = (r >> 3) & 3, jj = r & 7, nt = j >> 4, l15 = j & 15;
    AfqP[(((ch * 8 + nt) * 4 + quad) * 16 + l15) * 8 + jj] = f2bf(acc);
  } else if (r < 256) {
    int k = r - 128;  // input dim
    float acc = 0.f;
    for (int t = 0; t < 128; ++t) acc += Wk[k * 128 + t] * A1[(128 + t) * 128 + j];
    int ch = k >> 5, quad = (k >> 3) & 3, jj = k & 7, nt = j >> 4, l15 = j & 15;
    AfkP[(((ch * 8 + nt) * 4 + quad) * 16 + l15) * 8 + jj] = f2bf(acc);
  } else if (r < 320) {
    int k = r - 256;
    float acc = 0.f;
    for (int t = 0; t < 128; ++t) acc += We[k * 128 + t] * A1[(256 + t) * 128 + j];
    AfeT[j * 64 + k] = f2bf(acc);
  } else if (r == 320) {
    float acc = b1[j];
    for (int t = 0; t < 128; ++t) {
      acc += bq[t] * A1[t * 128 + j];
      acc += bk[t] * A1[(128 + t) * 128 + j];
      acc += be[t] * A1[(256 + t) * 128 + j];
    }
    bfold[j] = acc;
  } else if (r < 449) {
    int c = r - 321;  // outcol; thread j = input k
    int ch = j >> 5, quad = (j >> 3) & 3, jj = j & 7, nt = c >> 4, l15 = c & 15;
    WnP[(((ch * 8 + nt) * 4 + quad) * 16 + l15) * 8 + jj] = f2bf(Wn[j * 128 + c]);
  } else if (r < 577) {
    int c = r - 449;
    int ch = j >> 5, quad = (j >> 3) & 3, jj = j & 7, nt = c >> 4, l15 = c & 15;
    WvP[(((ch * 8 + nt) * 4 + quad) * 16 + l15) * 8 + jj] = f2bf(Wv[j * 128 + c]);
  } else {
    int i = (r - 577) * 128 + j;
    if (i < E) atomicAdd(&deg[src[i]], 1);
  }
}

// ---------------------------------------------------------------------------
// K1: FUSED node GEMMs via MFMA. One dispatch; each 128-row block stages the
// X-tile (fp32->bf16) into LDS ONCE (34KB, stride 136 = conflict-minimal for
// b128 fragment reads), then runs 4 GEMMs (Wn,Wv,Afq,Afk) sequentially from
// it, B read directly from global in fragment order (L2-resident tables).
// Cuts X HBM reads 102MB->25.6MB and cvt8 work 4x->1x vs 4-dispatch version.
// Mode loop is NOT unrolled (keeps acc=64 VGPR live once, no spill risk).
//  mode 0: h = X@Wn+bn (fp32)           mode 1: vb = bf16(X@Wv+bv)
//  mode 2: q2p = bf16(X@Af_q) permuted  mode 3: k2p = bf16(X@Af_k) permuted
__global__ __launch_bounds__(256, 2) void node_gemm_fused(
    const float* __restrict__ X, const ushort* __restrict__ WnP,
    const ushort* __restrict__ WvP, const ushort* __restrict__ AfqP,
    const ushort* __restrict__ AfkP, const float* __restrict__ bn,
    const float* __restrict__ bv, float* __restrict__ h,
    ushort* __restrict__ vb, ushort* __restrict__ q2p,
    ushort* __restrict__ k2p, int Nn) {
  __shared__ ushort As[128 * 136];  // 128 rows x 128 bf16, +8 pad
  __shared__ float bnS[128], bvS[128];
  const int t = threadIdx.x;
  if (t < 128) {
    bnS[t] = bn[t];
    bvS[t] = bv[t];
  }
  const int m0 = blockIdx.x * 128;
  {  // stage X-tile: 2 threads/row, 64 cols each
    int row = t >> 1, half = t & 1;
    int rg = min(m0 + row, Nn - 1);
    const float* xp = X + (size_t)rg * 128 + half * 64;
    ushort* ap = &As[row * 136 + half * 64];
#pragma unroll
    for (int s = 0; s < 8; ++s) *(uint4*)(ap + s * 8) = cvt8(xp + s * 8);
  }
  __syncthreads();
  const int lane = t & 63, wv = t >> 6, l15 = lane & 15, quad = lane >> 4;
#pragma unroll 1
  for (int mode = 0; mode < 4; ++mode) {
    const ushort* BP;
    switch (mode) {
      case 0: BP = WnP; break;
      case 1: BP = WvP; break;
      case 2: BP = AfqP; break;
      default: BP = AfkP; break;
    }
    f32x4 acc[2][8];
#pragma unroll
    for (int mt = 0; mt < 2; ++mt)
#pragma unroll
      for (int nt = 0; nt < 8; ++nt) acc[mt][nt] = (f32x4)(0.f);
#pragma unroll
    for (int ch = 0; ch < 4; ++ch) {
      bf16x8 af[2];
#pragma unroll
      for (int mt = 0; mt < 2; ++mt)
        af[mt] = *(const bf16x8*)&As[(wv * 32 + mt * 16 + l15) * 136 +
                                     ch * 32 + quad * 8];
      const ushort* bp = BP + ((size_t)(ch * 8) * 64 + lane) * 8;
#pragma unroll
      for (int nt = 0; nt < 8; ++nt) {
        bf16x8 bfr = *(const bf16x8*)(bp + nt * 512);
#pragma unroll
        for (int mt = 0; mt < 2; ++mt)
          acc[mt][nt] = __builtin_amdgcn_mfma_f32_16x16x32_bf16(
              af[mt], bfr, acc[mt][nt], 0, 0, 0);
      }
    }
    // epilogue for this mode
#pragma unroll
    for (int mt = 0; mt < 2; ++mt) {
      int rowb = m0 + wv * 32 + mt * 16 + quad * 4;
#pragma unroll
      for (int nt = 0; nt < 8; ++nt) {
        int col = nt * 16 + l15;
#pragma unroll
        for (int r = 0; r < 4; ++r) {
          int rg = rowb + r;
          if (rg < Nn) {
            if (mode == 0)
              h[(size_t)rg * 128 + col] = acc[mt][nt][r] + bnS[col];
            else if (mode == 1)
              vb[(size_t)rg * 128 + col] = f2bf(acc[mt][nt][r] + bvS[col]);
            else if (mode == 2)
              q2p[(size_t)rg * 128 + l15 * 8 + nt] = f2bf(acc[mt][nt][r]);
            else
              k2p[(size_t)rg * 128 + l15 * 8 + nt] = f2bf(acc[mt][nt][r]);
          }
        }
      }
    }
  }
}

// ---------------------------------------------------------------------------
// K2: streaming edge pipeline, 128 edges/block (M=32/wave), fused CSR-fill
// and per-block softmax partial.
// Occupancy history: (256,3) -> VGPR=84, 109us, no spill. KNOWN GOOD.
//   (256,4) -> allocator snapped to VGPR=64, spills (WRITE 58->111MB), 120us.
//   (256,5) -> VGPR=48, massive spills (WRITE 58->454MB), 230us.
// Rule: the allocator rounds to HW occupancy tiers; any min_waves>3 forces a
// tier below the natural 84 VGPRs and spills. DO NOT TOUCH.
__global__ __launch_bounds__(256, 3) void edge_fused4(
    const float* __restrict__ EF, const ushort* __restrict__ AfeT,
    const float* __restrict__ bfold, const float* __restrict__ A2,
    const float* __restrict__ b2, const ushort* __restrict__ q2p,
    const ushort* __restrict__ k2p, const int* __restrict__ src,
    const int* __restrict__ tgt, int* __restrict__ cursor,
    int2* __restrict__ cwt, float2* __restrict__ part, int E) {
  __shared__ ushort As[128 * 40];
  __shared__ ushort Bs[128 * 40];
  __shared__ float A2s[128 * 9];
  __shared__ float bfS[128];
  __shared__ float b2s[8];
  __shared__ int sIdxS[128], sIdxT[128];
  __shared__ float redM[16], redS[16];
  const int t = threadIdx.x;
  const int e0 = blockIdx.x * 128;
  if (t < 128) {
    sIdxS[t] = src[min(e0 + t, E - 1)];
    bfS[t] = bfold[t];
  } else {
    sIdxT[t - 128] = tgt[min(e0 + t - 128, E - 1)];
  }
  if (t < 8) b2s[t] = b2[t];
#pragma unroll
  for (int l = 0; l < 4; ++l) {
    int i = t + l * 256;
    A2s[(i >> 3) * 9 + (i & 7)] = A2[i];
  }
  const int seg = t & 3, arow = t >> 2;  // arow in [0,64)
  int ecl[2];
#pragma unroll
  for (int l = 0; l < 2; ++l) ecl[l] = min(e0 + arow + 64 * l, E - 1);
  uint4 avA[2], avB[2];
#pragma unroll
  for (int l = 0; l < 2; ++l) {
    avA[l] = cvt8(EF + (size_t)ecl[l] * 64 + seg * 8);
    avB[l] = *(const uint4*)(AfeT + (arow + 64 * l) * 64 + seg * 8);
  }
  f32x4 acc[2][8];
#pragma unroll
  for (int mt = 0; mt < 2; ++mt)
#pragma unroll
    for (int nt = 0; nt < 8; ++nt) acc[mt][nt] = (f32x4)(0.f);
  const int lane = t & 63, wv = t >> 6, l15 = lane & 15, quad = lane >> 4;

#pragma unroll
  for (int ch = 0; ch < 2; ++ch) {
#pragma unroll
    for (int l = 0; l < 2; ++l) {
      *(uint4*)&As[(arow + 64 * l) * 40 + seg * 8] = avA[l];
      *(uint4*)&Bs[(arow + 64 * l) * 40 + seg * 8] = avB[l];
    }
    __syncthreads();
    if (ch == 0) {
      int o = 32 + seg * 8;
#pragma unroll
      for (int l = 0; l < 2; ++l) {
        avA[l] = cvt8(EF + (size_t)ecl[l] * 64 + o);
        avB[l] = *(const uint4*)(AfeT + (arow + 64 * l) * 64 + o);
      }
    }
    bf16x8 af[2];
#pragma unroll
    for (int mt = 0; mt < 2; ++mt)
      af[mt] = *(const bf16x8*)&As[(wv * 32 + mt * 16 + l15) * 40 + quad * 8];
#pragma unroll
    for (int nt = 0; nt < 8; ++nt) {
      bf16x8 bfr = *(const bf16x8*)&Bs[(nt * 16 + l15) * 40 + quad * 8];
#pragma unroll
      for (int mt = 0; mt < 2; ++mt)
        acc[mt][nt] =
            __builtin_amdgcn_mfma_f32_16x16x32_bf16(af[mt], bfr, acc[mt][nt], 0, 0, 0);
    }
    if (ch == 0) __syncthreads();
  }

  // epilogue: gather q2/k2 (indices from LDS), bias + lrelu
  float bfv[8];
#pragma unroll
  for (int nt = 0; nt < 8; ++nt) bfv[nt] = bfS[nt * 16 + l15];
#pragma unroll
  for (int mt = 0; mt < 2; ++mt) {
#pragma unroll
    for (int r = 0; r < 4; ++r) {
      int erow = wv * 32 + mt * 16 + quad * 4 + r;
      int si = sIdxS[erow], ti = sIdxT[erow];
      uint4 qv = *(const uint4*)(q2p + (size_t)si * 128 + l15 * 8);
      uint4 kv = *(const uint4*)(k2p + (size_t)ti * 128 + l15 * 8);
      const ushort* qs = (const ushort*)&qv;
      const ushort* ks = (const ushort*)&kv;
#pragma unroll
      for (int nt = 0; nt < 8; ++nt)
        acc[mt][nt][r] =
            lrelu(acc[mt][nt][r] + bf2f(qs[nt]) + bf2f(ks[nt]) + bfv[nt]);
    }
  }
  // head stage: s = mean_h lrelu(hmid @ A2 + b2)
  float tacc[2][4];
#pragma unroll
  for (int mt = 0; mt < 2; ++mt)
#pragma unroll
    for (int r = 0; r < 4; ++r) tacc[mt][r] = 0.f;
  for (int hh = 0; hh < 8; ++hh) {
    float a2v[8];
#pragma unroll
    for (int nt = 0; nt < 8; ++nt) a2v[nt] = A2s[nt * 144 + l15 * 9 + hh];
    float b2h = b2s[hh];
#pragma unroll
    for (int mt = 0; mt < 2; ++mt)
#pragma unroll
      for (int r = 0; r < 4; ++r) {
        float p = 0.f;
#pragma unroll
        for (int nt = 0; nt < 8; ++nt) p += acc[mt][nt][r] * a2v[nt];
        p += __shfl_xor(p, 1);
        p += __shfl_xor(p, 2);
        p += __shfl_xor(p, 4);
        p += __shfl_xor(p, 8);
        tacc[mt][r] += lrelu(p + b2h);
      }
  }
  // l15==0 lanes: 8 scores each -> CSR fill + block softmax partial
  if (l15 == 0) {
    float sc[8];
    float m = -1e30f;
#pragma unroll
    for (int mt = 0; mt < 2; ++mt)
#pragma unroll
      for (int r = 0; r < 4; ++r) {
        int i = mt * 4 + r;
        sc[i] = tacc[mt][r] * 0.125f;
        int e = e0 + wv * 32 + mt * 16 + quad * 4 + r;
        if (e < E) m = fmaxf(m, sc[i]);
      }
    float ssum = 0.f;
#pragma unroll
    for (int mt = 0; mt < 2; ++mt)
#pragma unroll
      for (int r = 0; r < 4; ++r) {
        int i = mt * 4 + r;
        int erow = wv * 32 + mt * 16 + quad * 4 + r;
        if (e0 + erow < E) {
          ssum += __expf(sc[i] - m);
          int j = atomicAdd(&cursor[sIdxS[erow]], 1);
          cwt[j] = make_int2(sIdxT[erow], __float_as_int(sc[i]));
        }
      }
    int rid = wv * 4 + quad;
    redM[rid] = m;
    redS[rid] = ssum;
  }
  __syncthreads();
  if (t == 0) {
    float M = redM[0], S = redS[0];
#pragma unroll
    for (int i = 1; i < 16; ++i) {
      float m2 = redM[i], s2 = redS[i];
      float Mn = fmaxf(M, m2);
      S = S * __expf(M - Mn) + s2 * __expf(m2 - Mn);
      M = Mn;
    }
    part[blockIdx.x] = make_float2(M, S);
  }
}

// ---------------------------------------------------------------------------
// K3: final reduce of per-block partials -> MS[0]=M, MS[1]=1/sum
__global__ __launch_bounds__(256) void softmax_final(
    const float2* __restrict__ part, int nPart, float* __restrict__ MS) {
  __shared__ float mS[256], sS[256];
  int tid = threadIdx.x;
  float m = -1e30f, sum = 0.f;
  for (int i = tid; i < nPart; i += 256) {
    float2 p = part[i];
    float M = fmaxf(m, p.x);
    sum = sum * __expf(m - M) + p.y * __expf(p.x - M);
    m = M;
  }
  mS[tid] = m;
  sS[tid] = sum;
  __syncthreads();
  for (int off = 128; off > 0; off >>= 1) {
    if (tid < off) {
      float m1 = mS[tid], s1 = sS[tid];
      float m2 = mS[tid + off], s2 = sS[tid + off];
      float M = fmaxf(m1, m2);
      mS[tid] = M;
      sS[tid] = s1 * __expf(m1 - M) + s2 * __expf(m2 - M);
    }
    __syncthreads();
  }
  if (tid == 0) {
    MS[0] = mS[0];
    MS[1] = 1.f / sS[0];
  }
}

// ---------------------------------------------------------------------------
// CSR scan (exclusive prefix over deg)
__global__ __launch_bounds__(256) void scan1(const int* __restrict__ deg,
                                             int* __restrict__ incl,
                                             int* __restrict__ bsum, int N) {
  __shared__ int sh[256];
  int tid = threadIdx.x;
  int i = blockIdx.x * 256 + tid;
  sh[tid] = (i < N) ? deg[i] : 0;
  __syncthreads();
  for (int off = 1; off < 256; off <<= 1) {
    int tv = (tid >= off) ? sh[tid - off] : 0;
    __syncthreads();
    sh[tid] += tv;
    __syncthreads();
  }
  if (i < N) incl[i] = sh[tid];
  if (tid == 255) bsum[blockIdx.x] = sh[255];
}

__global__ __launch_bounds__(256) void scan2(int* __restrict__ bsum, int nb) {
  __shared__ int sh[256];
  int tid = threadIdx.x;
  sh[tid] = (tid < nb) ? bsum[tid] : 0;
  __syncthreads();
  for (int off = 1; off < 256; off <<= 1) {
    int tv = (tid >= off) ? sh[tid - off] : 0;
    __syncthreads();
    sh[tid] += tv;
    __syncthreads();
  }
  if (tid < nb) bsum[tid] = sh[tid];
}

__global__ __launch_bounds__(256) void scan3(const int* __restrict__ deg,
                                             const int* __restrict__ incl,
                                             const int* __restrict__ bsum,
                                             int* __restrict__ offs,
                                             int* __restrict__ cursor, int N,
                                             int E) {
  int i = blockIdx.x * 256 + threadIdx.x;
  if (i >= N) return;
  int base = (blockIdx.x > 0) ? bsum[blockIdx.x - 1] : 0;
  int ex = incl[i] - deg[i] + base;
  offs[i] = ex;
  cursor[i] = ex;
  if (i == N - 1) offs[N] = E;
}

// ---------------------------------------------------------------------------
// K5: fused gather (bf16 v) + softmax-normalize + layernorm, unroll x4.
__global__ __launch_bounds__(256) void gather_ln(
    const int* __restrict__ offs, const int2* __restrict__ cwt,
    const ushort* __restrict__ vb, const float* __restrict__ MS,
    const float* __restrict__ gamma, const float* __restrict__ beta,
    float* __restrict__ y, int N) {
  int tid = threadIdx.x;
  int n = blockIdx.x * 4 + (tid >> 6);
  if (n >= N) return;  // wave-uniform
  int lane = tid & 63;
  float M = MS[0], inv = MS[1];
  int beg = offs[n], end = offs[n + 1];
  float a0 = 0.f, a1 = 0.f;
  int j = beg;
  for (; j + 4 <= end; j += 4) {
    int2 p0 = cwt[j], p1 = cwt[j + 1], p2 = cwt[j + 2], p3 = cwt[j + 3];
    unsigned u0 = *(const unsigned*)(vb + (size_t)p0.x * 128 + lane * 2);
    unsigned u1 = *(const unsigned*)(vb + (size_t)p1.x * 128 + lane * 2);
    unsigned u2 = *(const unsigned*)(vb + (size_t)p2.x * 128 + lane * 2);
    unsigned u3 = *(const unsigned*)(vb + (size_t)p3.x * 128 + lane * 2);
    float w0 = __expf(__int_as_float(p0.y) - M) * inv;
    float w1 = __expf(__int_as_float(p1.y) - M) * inv;
    float w2 = __expf(__int_as_float(p2.y) - M) * inv;
    float w3 = __expf(__int_as_float(p3.y) - M) * inv;
    a0 += w0 * bf2f(u0 & 0xffffu) + w1 * bf2f(u1 & 0xffffu) +
          w2 * bf2f(u2 & 0xffffu) + w3 * bf2f(u3 & 0xffffu);
    a1 += w0 * bf2f(u0 >> 16) + w1 * bf2f(u1 >> 16) + w2 * bf2f(u2 >> 16) +
          w3 * bf2f(u3 >> 16);
  }
  for (; j < end; ++j) {
    int2 p = cwt[j];
    float w = __expf(__int_as_float(p.y) - M) * inv;
    unsigned u = *(const unsigned*)(vb + (size_t)p.x * 128 + lane * 2);
    a0 += w * bf2f(u & 0xffffu);
    a1 += w * bf2f(u >> 16);
  }
  size_t base = (size_t)n * 128 + lane * 2;
  float2 hv = *(const float2*)(y + base);
  float y0 = hv.x + a0, y1 = hv.y + a1;
  float sum = y0 + y1, ssq = y0 * y0 + y1 * y1;
#pragma unroll
  for (int off = 1; off < 64; off <<= 1) {
    sum += __shfl_xor(sum, off);
    ssq += __shfl_xor(ssq, off);
  }
  float mu = sum * (1.f / 128.f);
  float var = ssq * (1.f / 128.f) - mu * mu;
  float rstd = rsqrtf(var + EPS);
  float2 g = *(const float2*)(gamma + lane * 2);
  float2 bt = *(const float2*)(beta + lane * 2);
  float2 out;
  out.x = g.x * (y0 - mu) * rstd + bt.x;
  out.y = g.y * (y1 - mu) * rstd + bt.y;
  *(float2*)(y + base) = out;
}

// ---------------------------------------------------------------------------
extern "C" void kernel_launch(void* const* d_in, const int* in_sizes, int n_in,
                              void* d_out, int out_size, void* d_ws,
                              size_t ws_size, hipStream_t stream) {
  const float* X  = (const float*)d_in[0];
  const float* EF = (const float*)d_in[1];
  const float* Wn = (const float*)d_in[2];
  const float* bn = (const float*)d_in[3];
  const float* Wq = (const float*)d_in[4];
  const float* bq = (const float*)d_in[5];
  const float* Wk = (const float*)d_in[6];
  const float* bk = (const float*)d_in[7];
  const float* Wv = (const float*)d_in[8];
  const float* bv = (const float*)d_in[9];
  const float* We = (const float*)d_in[10];
  const float* be = (const float*)d_in[11];
  const float* A1 = (const float*)d_in[12];
  const float* b1 = (const float*)d_in[13];
  const float* A2 = (const float*)d_in[14];
  const float* b2 = (const float*)d_in[15];
  const float* gamma = (const float*)d_in[16];
  const float* beta  = (const float*)d_in[17];
  const int* ei = (const int*)d_in[18];

  int N = in_sizes[0] / D;   // 50000
  int E = in_sizes[1] / DE;  // 400000
  const int* src = ei;
  const int* tgt = ei + E;

  float* h = (float*)d_out;  // h accumulated/normalized in place
  float* ws = (float*)d_ws;
  float2* part = (float2*)ws;                          // 4096 cap
  float* MS    = (float*)(part + 4096);                // 4
  float* bfold = MS + 4;                               // 128
  ushort* vb   = (ushort*)(bfold + 128);               // N*128 bf16
  ushort* q2p  = vb + (size_t)N * D;                   // N*128
  ushort* k2p  = q2p + (size_t)N * D;                  // N*128
  ushort* AfqP = k2p + (size_t)N * D;                  // 128*128
  ushort* AfkP = AfqP + 128 * 128;                     // 128*128
  ushort* AfeT = AfkP + 128 * 128;                     // 128*64
  ushort* WnP  = AfeT + 128 * 64;                      // 128*128
  ushort* WvP  = WnP + 128 * 128;                      // 128*128
  int* deg    = (int*)(WvP + 128 * 128);               // N
  int* incl   = deg + N;                               // N
  int* bsum   = incl + N;                              // 256
  int* cursor = bsum + 256;                            // N
  int* offs   = cursor + N;                            // N+2
  int2* cwt   = (int2*)(offs + N + 2);                 // E

  int nbScan = (N + 255) / 256;          // 196 (<= 256)
  int nbEdge = (E + 127) / 128;          // 3125 (<= 4096 part cap)
  int nbHist = (E + 127) / 128;

  hipMemsetAsync(deg, 0, (size_t)N * sizeof(int), stream);
  fold_pack<<<577 + nbHist, 128, 0, stream>>>(Wq, Wk, We, A1, bq, bk, be, b1,
                                              Wn, Wv, AfqP, AfkP, AfeT, bfold,
                                              WnP, WvP, src, deg, E);
  scan1<<<nbScan, 256, 0, stream>>>(deg, incl, bsum, N);
  scan2<<<1, 256, 0, stream>>>(bsum, nbScan);
  scan3<<<nbScan, 256, 0, stream>>>(deg, incl, bsum, offs, cursor, N, E);
  node_gemm_fused<<<(N + 127) / 128, 256, 0, stream>>>(
      X, WnP, WvP, AfqP, AfkP, bn, bv, h, vb, q2p, k2p, N);
  edge_fused4<<<nbEdge, 256, 0, stream>>>(EF, AfeT, bfold, A2, b2, q2p, k2p,
                                          src, tgt, cursor, cwt, part, E);
  softmax_final<<<1, 256, 0, stream>>>(part, nbEdge, MS);
  gather_ln<<<(N + 3) / 4, 256, 0, stream>>>(offs, cwt, vb, MS, gamma, beta, h,
                                             N);
}

// Round 5
// 376.905 us; speedup vs baseline: 1.0520x; 1.0520x over previous
//
#include <hip/hip_runtime.h>

// N=50000, E=400000, D=128, DE=64, H=8
#define D 128
#define DE 64
#define SLOPE 0.2f
#define EPS 1e-5f

typedef float f32x4 __attribute__((ext_vector_type(4)));
typedef short bf16x8 __attribute__((ext_vector_type(8)));
typedef unsigned short ushort;

__device__ __forceinline__ float lrelu(float x) { return x > 0.f ? x : SLOPE * x; }

// fp32 -> bf16 RNE
__device__ __forceinline__ ushort f2bf(float x) {
  union { float f; unsigned u; } c; c.f = x;
  unsigned r = c.u + 0x7FFFu + ((c.u >> 16) & 1u);
  return (ushort)(r >> 16);
}
__device__ __forceinline__ float bf2f(unsigned u) {
  return __uint_as_float(u << 16);
}
__device__ __forceinline__ uint4 cvt8(const float* p) {
  float4 f0 = *(const float4*)p;
  float4 f1 = *(const float4*)(p + 4);
  union { ushort us[8]; uint4 v; } u;
  u.us[0] = f2bf(f0.x); u.us[1] = f2bf(f0.y);
  u.us[2] = f2bf(f0.z); u.us[3] = f2bf(f0.w);
  u.us[4] = f2bf(f1.x); u.us[5] = f2bf(f1.y);
  u.us[6] = f2bf(f1.z); u.us[7] = f2bf(f1.w);
  return u.v;
}

// ---------------------------------------------------------------------------
// K0: fold weights + pack bf16 tables + deg histogram (blocks >= 577).
// Histogram now ALSO persists each edge's within-node rank (the atomicAdd
// return value) so edge_fused4 can compute its CSR slot without atomics:
// slot = offs[src] + rank[e].
// WnP/WvP/AfqP/AfkP are emitted in MFMA B-FRAGMENT order (L2-resident reads
// in node_gemm, no LDS staging):
//   element (outcol, k) -> idx = (((ch*8+nt)*4+quad)*16+l15)*8+jj
//   where nt=outcol>>4, l15=outcol&15, ch=k>>5, quad=(k>>3)&3, jj=k&7.
// AfeT keeps the old [outcol][k] layout (consumed by edge_fused4's LDS path).
__global__ __launch_bounds__(128) void fold_pack(
    const float* __restrict__ Wq, const float* __restrict__ Wk,
    const float* __restrict__ We, const float* __restrict__ A1,
    const float* __restrict__ bq, const float* __restrict__ bk,
    const float* __restrict__ be, const float* __restrict__ b1,
    const float* __restrict__ Wn, const float* __restrict__ Wv,
    ushort* __restrict__ AfqP, ushort* __restrict__ AfkP,
    ushort* __restrict__ AfeT, float* __restrict__ bfold,
    ushort* __restrict__ WnP, ushort* __restrict__ WvP,
    const int* __restrict__ src, int* __restrict__ deg,
    int* __restrict__ rank, int E) {
  int r = blockIdx.x;
  int j = threadIdx.x;
  if (r < 128) {
    // F_q[k=r][outcol=j]
    float acc = 0.f;
    for (int t = 0; t < 128; ++t) acc += Wq[r * 128 + t] * A1[t * 128 + j];
    int ch = r >> 5, quad = (r >> 3) & 3, jj = r & 7, nt = j >> 4, l15 = j & 15;
    AfqP[(((ch * 8 + nt) * 4 + quad) * 16 + l15) * 8 + jj] = f2bf(acc);
  } else if (r < 256) {
    int k = r - 128;  // input dim
    float acc = 0.f;
    for (int t = 0; t < 128; ++t) acc += Wk[k * 128 + t] * A1[(128 + t) * 128 + j];
    int ch = k >> 5, quad = (k >> 3) & 3, jj = k & 7, nt = j >> 4, l15 = j & 15;
    AfkP[(((ch * 8 + nt) * 4 + quad) * 16 + l15) * 8 + jj] = f2bf(acc);
  } else if (r < 320) {
    int k = r - 256;
    float acc = 0.f;
    for (int t = 0; t < 128; ++t) acc += We[k * 128 + t] * A1[(256 + t) * 128 + j];
    AfeT[j * 64 + k] = f2bf(acc);
  } else if (r == 320) {
    float acc = b1[j];
    for (int t = 0; t < 128; ++t) {
      acc += bq[t] * A1[t * 128 + j];
      acc += bk[t] * A1[(128 + t) * 128 + j];
      acc += be[t] * A1[(256 + t) * 128 + j];
    }
    bfold[j] = acc;
  } else if (r < 449) {
    int c = r - 321;  // outcol; thread j = input k
    int ch = j >> 5, quad = (j >> 3) & 3, jj = j & 7, nt = c >> 4, l15 = c & 15;
    WnP[(((ch * 8 + nt) * 4 + quad) * 16 + l15) * 8 + jj] = f2bf(Wn[j * 128 + c]);
  } else if (r < 577) {
    int c = r - 449;
    int ch = j >> 5, quad = (j >> 3) & 3, jj = j & 7, nt = c >> 4, l15 = c & 15;
    WvP[(((ch * 8 + nt) * 4 + quad) * 16 + l15) * 8 + jj] = f2bf(Wv[j * 128 + c]);
  } else {
    int i = (r - 577) * 128 + j;
    if (i < E) rank[i] = atomicAdd(&deg[src[i]], 1);
  }
}

// ---------------------------------------------------------------------------
// K1: node GEMMs via MFMA, X converted fp32->bf16 inline. ROUND-3 version
// (4 dispatches via blockIdx.y, 128-row M-tile, B direct-from-global in
// fragment order). Round-4's single-dispatch fusion REGRESSED (+15us): only
// 391 blocks = 1.5 blocks/CU serializing 4 GEMMs -- parallelism beats
// traffic on this latency-bound pipeline. DO NOT re-fuse.
//  y=0: h = X@Wn+bn (fp32)              y=1: vb = bf16(X@Wv+bv)
//  y=2: q2p = bf16(X@Af_q) permuted     y=3: k2p = bf16(X@Af_k) permuted
__global__ __launch_bounds__(256, 2) void node_gemm_mfma(
    const float* __restrict__ X, const ushort* __restrict__ WnP,
    const ushort* __restrict__ WvP, const ushort* __restrict__ AfqP,
    const ushort* __restrict__ AfkP, const float* __restrict__ bn,
    const float* __restrict__ bv, float* __restrict__ h,
    ushort* __restrict__ vb, ushort* __restrict__ q2p,
    ushort* __restrict__ k2p, int Nn) {
  __shared__ ushort As[128 * 40];
  __shared__ float bS[128];
  const ushort* BP;
  const float* bb = nullptr;
  float* O = nullptr;
  ushort* Ob = nullptr;
  int mode;
  switch (blockIdx.y) {
    case 0: BP = WnP; bb = bn; O = h; mode = 0; break;
    case 1: BP = WvP; bb = bv; Ob = vb; mode = 1; break;
    case 2: BP = AfqP; Ob = q2p; mode = 2; break;
    default: BP = AfkP; Ob = k2p; mode = 2; break;
  }
  const int t = threadIdx.x;
  if (t < 128) bS[t] = bb ? bb[t] : 0.f;
  const int seg = t & 3, arow = t >> 2;  // arow in [0,64)
  const int m0 = blockIdx.x * 128;
  int rIdx[2];
#pragma unroll
  for (int l = 0; l < 2; ++l) rIdx[l] = min(m0 + arow + 64 * l, Nn - 1);
  uint4 avA[2];
#pragma unroll
  for (int l = 0; l < 2; ++l)
    avA[l] = cvt8(X + (size_t)rIdx[l] * 128 + seg * 8);
  f32x4 acc[2][8];
#pragma unroll
  for (int mt = 0; mt < 2; ++mt)
#pragma unroll
    for (int nt = 0; nt < 8; ++nt) acc[mt][nt] = (f32x4)(0.f);
  const int lane = t & 63, wv = t >> 6, l15 = lane & 15, quad = lane >> 4;
  for (int ch = 0; ch < 4; ++ch) {
#pragma unroll
    for (int l = 0; l < 2; ++l)
      *(uint4*)&As[(arow + 64 * l) * 40 + seg * 8] = avA[l];
    __syncthreads();
    if (ch < 3) {
      int o = (ch + 1) * 32 + seg * 8;
#pragma unroll
      for (int l = 0; l < 2; ++l)
        avA[l] = cvt8(X + (size_t)rIdx[l] * 128 + o);
    }
    bf16x8 af[2];
#pragma unroll
    for (int mt = 0; mt < 2; ++mt)
      af[mt] = *(const bf16x8*)&As[(wv * 32 + mt * 16 + l15) * 40 + quad * 8];
    // B fragments straight from global (fragment-ordered, L2-resident):
    const ushort* bp = BP + ((size_t)(ch * 8) * 64 + lane) * 8;
#pragma unroll
    for (int nt = 0; nt < 8; ++nt) {
      bf16x8 bfr = *(const bf16x8*)(bp + nt * 512);
#pragma unroll
      for (int mt = 0; mt < 2; ++mt)
        acc[mt][nt] =
            __builtin_amdgcn_mfma_f32_16x16x32_bf16(af[mt], bfr, acc[mt][nt], 0, 0, 0);
    }
    __syncthreads();
  }
#pragma unroll
  for (int mt = 0; mt < 2; ++mt) {
    int rowb = m0 + wv * 32 + mt * 16 + quad * 4;
#pragma unroll
    for (int nt = 0; nt < 8; ++nt) {
      int col = nt * 16 + l15;
      float b = bS[col];
#pragma unroll
      for (int r = 0; r < 4; ++r) {
        int rg = rowb + r;
        if (rg < Nn) {
          if (mode == 0)      O[(size_t)rg * 128 + col] = acc[mt][nt][r] + b;
          else if (mode == 1) Ob[(size_t)rg * 128 + col] = f2bf(acc[mt][nt][r] + b);
          else                Ob[(size_t)rg * 128 + l15 * 8 + nt] = f2bf(acc[mt][nt][r]);
        }
      }
    }
  }
}

// ---------------------------------------------------------------------------
// K2: streaming edge pipeline, 128 edges/block (M=32/wave), fused CSR-fill
// and per-block softmax partial. CSR slot now ATOMIC-FREE:
// slot = offs[src] + rank[e] (rank persisted by fold_pack's histogram), so
// the 8 scatter stores per l15==0 lane are independent (previously 8
// dependent atomicAdd->store round-trips on contended cursor lines).
// Occupancy history: (256,3) -> VGPR=84, 109us, no spill. KNOWN GOOD.
//   (256,4) -> allocator snapped to VGPR=64, spills (WRITE 58->111MB), 120us.
//   (256,5) -> VGPR=48, massive spills (WRITE 58->454MB), 230us.
// Rule: allocator rounds to HW occupancy tiers; min_waves>3 forces a tier
// below the natural ~84 VGPRs and spills. DO NOT TOUCH the (256,3).
__global__ __launch_bounds__(256, 3) void edge_fused4(
    const float* __restrict__ EF, const ushort* __restrict__ AfeT,
    const float* __restrict__ bfold, const float* __restrict__ A2,
    const float* __restrict__ b2, const ushort* __restrict__ q2p,
    const ushort* __restrict__ k2p, const int* __restrict__ src,
    const int* __restrict__ tgt, const int* __restrict__ offs,
    const int* __restrict__ rank,
    int2* __restrict__ cwt, float2* __restrict__ part, int E) {
  __shared__ ushort As[128 * 40];
  __shared__ ushort Bs[128 * 40];
  __shared__ float A2s[128 * 9];
  __shared__ float bfS[128];
  __shared__ float b2s[8];
  __shared__ int sIdxS[128], sIdxT[128], sRank[128];
  __shared__ float redM[16], redS[16];
  const int t = threadIdx.x;
  const int e0 = blockIdx.x * 128;
  if (t < 128) {
    int ec = min(e0 + t, E - 1);
    sIdxS[t] = src[ec];
    sRank[t] = rank[ec];
    bfS[t] = bfold[t];
  } else {
    sIdxT[t - 128] = tgt[min(e0 + t - 128, E - 1)];
  }
  if (t < 8) b2s[t] = b2[t];
#pragma unroll
  for (int l = 0; l < 4; ++l) {
    int i = t + l * 256;
    A2s[(i >> 3) * 9 + (i & 7)] = A2[i];
  }
  const int seg = t & 3, arow = t >> 2;  // arow in [0,64)
  int ecl[2];
#pragma unroll
  for (int l = 0; l < 2; ++l) ecl[l] = min(e0 + arow + 64 * l, E - 1);
  uint4 avA[2], avB[2];
#pragma unroll
  for (int l = 0; l < 2; ++l) {
    avA[l] = cvt8(EF + (size_t)ecl[l] * 64 + seg * 8);
    avB[l] = *(const uint4*)(AfeT + (arow + 64 * l) * 64 + seg * 8);
  }
  f32x4 acc[2][8];
#pragma unroll
  for (int mt = 0; mt < 2; ++mt)
#pragma unroll
    for (int nt = 0; nt < 8; ++nt) acc[mt][nt] = (f32x4)(0.f);
  const int lane = t & 63, wv = t >> 6, l15 = lane & 15, quad = lane >> 4;

#pragma unroll
  for (int ch = 0; ch < 2; ++ch) {
#pragma unroll
    for (int l = 0; l < 2; ++l) {
      *(uint4*)&As[(arow + 64 * l) * 40 + seg * 8] = avA[l];
      *(uint4*)&Bs[(arow + 64 * l) * 40 + seg * 8] = avB[l];
    }
    __syncthreads();
    if (ch == 0) {
      int o = 32 + seg * 8;
#pragma unroll
      for (int l = 0; l < 2; ++l) {
        avA[l] = cvt8(EF + (size_t)ecl[l] * 64 + o);
        avB[l] = *(const uint4*)(AfeT + (arow + 64 * l) * 64 + o);
      }
    }
    bf16x8 af[2];
#pragma unroll
    for (int mt = 0; mt < 2; ++mt)
      af[mt] = *(const bf16x8*)&As[(wv * 32 + mt * 16 + l15) * 40 + quad * 8];
#pragma unroll
    for (int nt = 0; nt < 8; ++nt) {
      bf16x8 bfr = *(const bf16x8*)&Bs[(nt * 16 + l15) * 40 + quad * 8];
#pragma unroll
      for (int mt = 0; mt < 2; ++mt)
        acc[mt][nt] =
            __builtin_amdgcn_mfma_f32_16x16x32_bf16(af[mt], bfr, acc[mt][nt], 0, 0, 0);
    }
    if (ch == 0) __syncthreads();
  }

  // epilogue: gather q2/k2 (indices from LDS), bias + lrelu
  float bfv[8];
#pragma unroll
  for (int nt = 0; nt < 8; ++nt) bfv[nt] = bfS[nt * 16 + l15];
#pragma unroll
  for (int mt = 0; mt < 2; ++mt) {
#pragma unroll
    for (int r = 0; r < 4; ++r) {
      int erow = wv * 32 + mt * 16 + quad * 4 + r;
      int si = sIdxS[erow], ti = sIdxT[erow];
      uint4 qv = *(const uint4*)(q2p + (size_t)si * 128 + l15 * 8);
      uint4 kv = *(const uint4*)(k2p + (size_t)ti * 128 + l15 * 8);
      const ushort* qs = (const ushort*)&qv;
      const ushort* ks = (const ushort*)&kv;
#pragma unroll
      for (int nt = 0; nt < 8; ++nt)
        acc[mt][nt][r] =
            lrelu(acc[mt][nt][r] + bf2f(qs[nt]) + bf2f(ks[nt]) + bfv[nt]);
    }
  }
  // head stage: s = mean_h lrelu(hmid @ A2 + b2)
  float tacc[2][4];
#pragma unroll
  for (int mt = 0; mt < 2; ++mt)
#pragma unroll
    for (int r = 0; r < 4; ++r) tacc[mt][r] = 0.f;
  for (int hh = 0; hh < 8; ++hh) {
    float a2v[8];
#pragma unroll
    for (int nt = 0; nt < 8; ++nt) a2v[nt] = A2s[nt * 144 + l15 * 9 + hh];
    float b2h = b2s[hh];
#pragma unroll
    for (int mt = 0; mt < 2; ++mt)
#pragma unroll
      for (int r = 0; r < 4; ++r) {
        float p = 0.f;
#pragma unroll
        for (int nt = 0; nt < 8; ++nt) p += acc[mt][nt][r] * a2v[nt];
        p += __shfl_xor(p, 1);
        p += __shfl_xor(p, 2);
        p += __shfl_xor(p, 4);
        p += __shfl_xor(p, 8);
        tacc[mt][r] += lrelu(p + b2h);
      }
  }
  // l15==0 lanes: 8 scores each -> CSR fill (atomic-free) + softmax partial
  if (l15 == 0) {
    float sc[8];
    float m = -1e30f;
#pragma unroll
    for (int mt = 0; mt < 2; ++mt)
#pragma unroll
      for (int r = 0; r < 4; ++r) {
        int i = mt * 4 + r;
        sc[i] = tacc[mt][r] * 0.125f;
        int e = e0 + wv * 32 + mt * 16 + quad * 4 + r;
        if (e < E) m = fmaxf(m, sc[i]);
      }
    float ssum = 0.f;
#pragma unroll
    for (int mt = 0; mt < 2; ++mt)
#pragma unroll
      for (int r = 0; r < 4; ++r) {
        int i = mt * 4 + r;
        int erow = wv * 32 + mt * 16 + quad * 4 + r;
        if (e0 + erow < E) {
          ssum += __expf(sc[i] - m);
          int j = offs[sIdxS[erow]] + sRank[erow];
          cwt[j] = make_int2(sIdxT[erow], __float_as_int(sc[i]));
        }
      }
    int rid = wv * 4 + quad;
    redM[rid] = m;
    redS[rid] = ssum;
  }
  __syncthreads();
  if (t == 0) {
    float M = redM[0], S = redS[0];
#pragma unroll
    for (int i = 1; i < 16; ++i) {
      float m2 = redM[i], s2 = redS[i];
      float Mn = fmaxf(M, m2);
      S = S * __expf(M - Mn) + s2 * __expf(m2 - Mn);
      M = Mn;
    }
    part[blockIdx.x] = make_float2(M, S);
  }
}

// ---------------------------------------------------------------------------
// K3: final reduce of per-block partials -> MS[0]=M, MS[1]=1/sum
__global__ __launch_bounds__(256) void softmax_final(
    const float2* __restrict__ part, int nPart, float* __restrict__ MS) {
  __shared__ float mS[256], sS[256];
  int tid = threadIdx.x;
  float m = -1e30f, sum = 0.f;
  for (int i = tid; i < nPart; i += 256) {
    float2 p = part[i];
    float M = fmaxf(m, p.x);
    sum = sum * __expf(m - M) + p.y * __expf(p.x - M);
    m = M;
  }
  mS[tid] = m;
  sS[tid] = sum;
  __syncthreads();
  for (int off = 128; off > 0; off >>= 1) {
    if (tid < off) {
      float m1 = mS[tid], s1 = sS[tid];
      float m2 = mS[tid + off], s2 = sS[tid + off];
      float M = fmaxf(m1, m2);
      mS[tid] = M;
      sS[tid] = s1 * __expf(m1 - M) + s2 * __expf(m2 - M);
    }
    __syncthreads();
  }
  if (tid == 0) {
    MS[0] = mS[0];
    MS[1] = 1.f / sS[0];
  }
}

// ---------------------------------------------------------------------------
// CSR scan (exclusive prefix over deg)
__global__ __launch_bounds__(256) void scan1(const int* __restrict__ deg,
                                             int* __restrict__ incl,
                                             int* __restrict__ bsum, int N) {
  __shared__ int sh[256];
  int tid = threadIdx.x;
  int i = blockIdx.x * 256 + tid;
  sh[tid] = (i < N) ? deg[i] : 0;
  __syncthreads();
  for (int off = 1; off < 256; off <<= 1) {
    int tv = (tid >= off) ? sh[tid - off] : 0;
    __syncthreads();
    sh[tid] += tv;
    __syncthreads();
  }
  if (i < N) incl[i] = sh[tid];
  if (tid == 255) bsum[blockIdx.x] = sh[255];
}

__global__ __launch_bounds__(256) void scan2(int* __restrict__ bsum, int nb) {
  __shared__ int sh[256];
  int tid = threadIdx.x;
  sh[tid] = (tid < nb) ? bsum[tid] : 0;
  __syncthreads();
  for (int off = 1; off < 256; off <<= 1) {
    int tv = (tid >= off) ? sh[tid - off] : 0;
    __syncthreads();
    sh[tid] += tv;
    __syncthreads();
  }
  if (tid < nb) bsum[tid] = sh[tid];
}

__global__ __launch_bounds__(256) void scan3(const int* __restrict__ deg,
                                             const int* __restrict__ incl,
                                             const int* __restrict__ bsum,
                                             int* __restrict__ offs, int N,
                                             int E) {
  int i = blockIdx.x * 256 + threadIdx.x;
  if (i >= N) return;
  int base = (blockIdx.x > 0) ? bsum[blockIdx.x - 1] : 0;
  int ex = incl[i] - deg[i] + base;
  offs[i] = ex;
  if (i == N - 1) offs[N] = E;
}

// ---------------------------------------------------------------------------
// K5: fused gather (bf16 v) + softmax-normalize + layernorm, unroll x4.
__global__ __launch_bounds__(256) void gather_ln(
    const int* __restrict__ offs, const int2* __restrict__ cwt,
    const ushort* __restrict__ vb, const float* __restrict__ MS,
    const float* __restrict__ gamma, const float* __restrict__ beta,
    float* __restrict__ y, int N) {
  int tid = threadIdx.x;
  int n = blockIdx.x * 4 + (tid >> 6);
  if (n >= N) return;  // wave-uniform
  int lane = tid & 63;
  float M = MS[0], inv = MS[1];
  int beg = offs[n], end = offs[n + 1];
  float a0 = 0.f, a1 = 0.f;
  int j = beg;
  for (; j + 4 <= end; j += 4) {
    int2 p0 = cwt[j], p1 = cwt[j + 1], p2 = cwt[j + 2], p3 = cwt[j + 3];
    unsigned u0 = *(const unsigned*)(vb + (size_t)p0.x * 128 + lane * 2);
    unsigned u1 = *(const unsigned*)(vb + (size_t)p1.x * 128 + lane * 2);
    unsigned u2 = *(const unsigned*)(vb + (size_t)p2.x * 128 + lane * 2);
    unsigned u3 = *(const unsigned*)(vb + (size_t)p3.x * 128 + lane * 2);
    float w0 = __expf(__int_as_float(p0.y) - M) * inv;
    float w1 = __expf(__int_as_float(p1.y) - M) * inv;
    float w2 = __expf(__int_as_float(p2.y) - M) * inv;
    float w3 = __expf(__int_as_float(p3.y) - M) * inv;
    a0 += w0 * bf2f(u0 & 0xffffu) + w1 * bf2f(u1 & 0xffffu) +
          w2 * bf2f(u2 & 0xffffu) + w3 * bf2f(u3 & 0xffffu);
    a1 += w0 * bf2f(u0 >> 16) + w1 * bf2f(u1 >> 16) + w2 * bf2f(u2 >> 16) +
          w3 * bf2f(u3 >> 16);
  }
  for (; j < end; ++j) {
    int2 p = cwt[j];
    float w = __expf(__int_as_float(p.y) - M) * inv;
    unsigned u = *(const unsigned*)(vb + (size_t)p.x * 128 + lane * 2);
    a0 += w * bf2f(u & 0xffffu);
    a1 += w * bf2f(u >> 16);
  }
  size_t base = (size_t)n * 128 + lane * 2;
  float2 hv = *(const float2*)(y + base);
  float y0 = hv.x + a0, y1 = hv.y + a1;
  float sum = y0 + y1, ssq = y0 * y0 + y1 * y1;
#pragma unroll
  for (int off = 1; off < 64; off <<= 1) {
    sum += __shfl_xor(sum, off);
    ssq += __shfl_xor(ssq, off);
  }
  float mu = sum * (1.f / 128.f);
  float var = ssq * (1.f / 128.f) - mu * mu;
  float rstd = rsqrtf(var + EPS);
  float2 g = *(const float2*)(gamma + lane * 2);
  float2 bt = *(const float2*)(beta + lane * 2);
  float2 out;
  out.x = g.x * (y0 - mu) * rstd + bt.x;
  out.y = g.y * (y1 - mu) * rstd + bt.y;
  *(float2*)(y + base) = out;
}

// ---------------------------------------------------------------------------
extern "C" void kernel_launch(void* const* d_in, const int* in_sizes, int n_in,
                              void* d_out, int out_size, void* d_ws,
                              size_t ws_size, hipStream_t stream) {
  const float* X  = (const float*)d_in[0];
  const float* EF = (const float*)d_in[1];
  const float* Wn = (const float*)d_in[2];
  const float* bn = (const float*)d_in[3];
  const float* Wq = (const float*)d_in[4];
  const float* bq = (const float*)d_in[5];
  const float* Wk = (const float*)d_in[6];
  const float* bk = (const float*)d_in[7];
  const float* Wv = (const float*)d_in[8];
  const float* bv = (const float*)d_in[9];
  const float* We = (const float*)d_in[10];
  const float* be = (const float*)d_in[11];
  const float* A1 = (const float*)d_in[12];
  const float* b1 = (const float*)d_in[13];
  const float* A2 = (const float*)d_in[14];
  const float* b2 = (const float*)d_in[15];
  const float* gamma = (const float*)d_in[16];
  const float* beta  = (const float*)d_in[17];
  const int* ei = (const int*)d_in[18];

  int N = in_sizes[0] / D;   // 50000
  int E = in_sizes[1] / DE;  // 400000
  const int* src = ei;
  const int* tgt = ei + E;

  float* h = (float*)d_out;  // h accumulated/normalized in place
  float* ws = (float*)d_ws;
  float2* part = (float2*)ws;                          // 4096 cap
  float* MS    = (float*)(part + 4096);                // 4
  float* bfold = MS + 4;                               // 128
  ushort* vb   = (ushort*)(bfold + 128);               // N*128 bf16
  ushort* q2p  = vb + (size_t)N * D;                   // N*128
  ushort* k2p  = q2p + (size_t)N * D;                  // N*128
  ushort* AfqP = k2p + (size_t)N * D;                  // 128*128
  ushort* AfkP = AfqP + 128 * 128;                     // 128*128
  ushort* AfeT = AfkP + 128 * 128;                     // 128*64
  ushort* WnP  = AfeT + 128 * 64;                      // 128*128
  ushort* WvP  = WnP + 128 * 128;                      // 128*128
  int* deg    = (int*)(WvP + 128 * 128);               // N
  int* incl   = deg + N;                               // N
  int* bsum   = incl + N;                              // 256
  int* rank   = bsum + 256;                            // E
  int* offs   = rank + E;                              // N+2
  int2* cwt   = (int2*)(offs + N + 2);                 // E

  int nbScan = (N + 255) / 256;          // 196 (<= 256)
  int nbEdge = (E + 127) / 128;          // 3125 (<= 4096 part cap)
  int nbHist = (E + 127) / 128;

  hipMemsetAsync(deg, 0, (size_t)N * sizeof(int), stream);
  fold_pack<<<577 + nbHist, 128, 0, stream>>>(Wq, Wk, We, A1, bq, bk, be, b1,
                                              Wn, Wv, AfqP, AfkP, AfeT, bfold,
                                              WnP, WvP, src, deg, rank, E);
  scan1<<<nbScan, 256, 0, stream>>>(deg, incl, bsum, N);
  scan2<<<1, 256, 0, stream>>>(bsum, nbScan);
  scan3<<<nbScan, 256, 0, stream>>>(deg, incl, bsum, offs, N, E);
  node_gemm_mfma<<<dim3((N + 127) / 128, 4), 256, 0, stream>>>(
      X, WnP, WvP, AfqP, AfkP, bn, bv, h, vb, q2p, k2p, N);
  edge_fused4<<<nbEdge, 256, 0, stream>>>(EF, AfeT, bfold, A2, b2, q2p, k2p,
                                          src, tgt, offs, rank, cwt, part, E);
  softmax_final<<<1, 256, 0, stream>>>(part, nbEdge, MS);
  gather_ln<<<(N + 3) / 4, 256, 0, stream>>>(offs, cwt, vb, MS, gamma, beta, h,
                                             N);
}

// Round 6
// 369.742 us; speedup vs baseline: 1.0724x; 1.0194x over previous
//
#include <hip/hip_runtime.h>

// N=50000, E=400000, D=128, DE=64, H=8
#define D 128
#define DE 64
#define SLOPE 0.2f
#define EPS 1e-5f

typedef float f32x4 __attribute__((ext_vector_type(4)));
typedef short bf16x8 __attribute__((ext_vector_type(8)));
typedef unsigned short ushort;

__device__ __forceinline__ float lrelu(float x) { return x > 0.f ? x : SLOPE * x; }

// fp32 -> bf16 RNE
__device__ __forceinline__ ushort f2bf(float x) {
  union { float f; unsigned u; } c; c.f = x;
  unsigned r = c.u + 0x7FFFu + ((c.u >> 16) & 1u);
  return (ushort)(r >> 16);
}
__device__ __forceinline__ float bf2f(unsigned u) {
  return __uint_as_float(u << 16);
}
__device__ __forceinline__ uint4 cvt8(const float* p) {
  float4 f0 = *(const float4*)p;
  float4 f1 = *(const float4*)(p + 4);
  union { ushort us[8]; uint4 v; } u;
  u.us[0] = f2bf(f0.x); u.us[1] = f2bf(f0.y);
  u.us[2] = f2bf(f0.z); u.us[3] = f2bf(f0.w);
  u.us[4] = f2bf(f1.x); u.us[5] = f2bf(f1.y);
  u.us[6] = f2bf(f1.z); u.us[7] = f2bf(f1.w);
  return u.v;
}

// ---------------------------------------------------------------------------
// K0: fold weights + pack bf16 tables + deg histogram (blocks >= 577).
// Histogram persists each edge's within-node rank (atomicAdd return) so
// edge_fused4 computes its CSR slot atomic-free: slot = offs[src] + rank[e].
// ALL B-operand tables (WnP/WvP/AfqP/AfkP and now AfeP) are emitted in MFMA
// B-FRAGMENT order so consumers read them directly from global (L2-resident,
// no LDS staging):
//   element (outcol, k) -> idx = (((ch*8+nt)*4+quad)*16+l15)*8+jj
//   where nt=outcol>>4, l15=outcol&15, ch=k>>5, quad=(k>>3)&3, jj=k&7.
__global__ __launch_bounds__(128) void fold_pack(
    const float* __restrict__ Wq, const float* __restrict__ Wk,
    const float* __restrict__ We, const float* __restrict__ A1,
    const float* __restrict__ bq, const float* __restrict__ bk,
    const float* __restrict__ be, const float* __restrict__ b1,
    const float* __restrict__ Wn, const float* __restrict__ Wv,
    ushort* __restrict__ AfqP, ushort* __restrict__ AfkP,
    ushort* __restrict__ AfeP, float* __restrict__ bfold,
    ushort* __restrict__ WnP, ushort* __restrict__ WvP,
    const int* __restrict__ src, int* __restrict__ deg,
    int* __restrict__ rank, int E) {
  int r = blockIdx.x;
  int j = threadIdx.x;
  if (r < 128) {
    // F_q[k=r][outcol=j]
    float acc = 0.f;
    for (int t = 0; t < 128; ++t) acc += Wq[r * 128 + t] * A1[t * 128 + j];
    int ch = r >> 5, quad = (r >> 3) & 3, jj = r & 7, nt = j >> 4, l15 = j & 15;
    AfqP[(((ch * 8 + nt) * 4 + quad) * 16 + l15) * 8 + jj] = f2bf(acc);
  } else if (r < 256) {
    int k = r - 128;  // input dim
    float acc = 0.f;
    for (int t = 0; t < 128; ++t) acc += Wk[k * 128 + t] * A1[(128 + t) * 128 + j];
    int ch = k >> 5, quad = (k >> 3) & 3, jj = k & 7, nt = j >> 4, l15 = j & 15;
    AfkP[(((ch * 8 + nt) * 4 + quad) * 16 + l15) * 8 + jj] = f2bf(acc);
  } else if (r < 320) {
    int k = r - 256;  // input dim in [0,64)
    float acc = 0.f;
    for (int t = 0; t < 128; ++t) acc += We[k * 128 + t] * A1[(256 + t) * 128 + j];
    // fragment order (K=64 -> ch in {0,1}), outcol = j
    int ch = k >> 5, quad = (k >> 3) & 3, jj = k & 7, nt = j >> 4, l15 = j & 15;
    AfeP[(((ch * 8 + nt) * 4 + quad) * 16 + l15) * 8 + jj] = f2bf(acc);
  } else if (r == 320) {
    float acc = b1[j];
    for (int t = 0; t < 128; ++t) {
      acc += bq[t] * A1[t * 128 + j];
      acc += bk[t] * A1[(128 + t) * 128 + j];
      acc += be[t] * A1[(256 + t) * 128 + j];
    }
    bfold[j] = acc;
  } else if (r < 449) {
    int c = r - 321;  // outcol; thread j = input k
    int ch = j >> 5, quad = (j >> 3) & 3, jj = j & 7, nt = c >> 4, l15 = c & 15;
    WnP[(((ch * 8 + nt) * 4 + quad) * 16 + l15) * 8 + jj] = f2bf(Wn[j * 128 + c]);
  } else if (r < 577) {
    int c = r - 449;
    int ch = j >> 5, quad = (j >> 3) & 3, jj = j & 7, nt = c >> 4, l15 = c & 15;
    WvP[(((ch * 8 + nt) * 4 + quad) * 16 + l15) * 8 + jj] = f2bf(Wv[j * 128 + c]);
  } else {
    int i = (r - 577) * 128 + j;
    if (i < E) rank[i] = atomicAdd(&deg[src[i]], 1);
  }
}

// ---------------------------------------------------------------------------
// K1: node GEMMs via MFMA, X converted fp32->bf16 inline. ROUND-3 version
// (4 dispatches via blockIdx.y, 128-row M-tile, B direct-from-global in
// fragment order). Round-4's single-dispatch fusion REGRESSED (+15us): only
// 391 blocks = 1.5 blocks/CU serializing 4 GEMMs -- parallelism beats
// traffic on this latency-bound pipeline. DO NOT re-fuse.
//  y=0: h = X@Wn+bn (fp32)              y=1: vb = bf16(X@Wv+bv)
//  y=2: q2p = bf16(X@Af_q) permuted     y=3: k2p = bf16(X@Af_k) permuted
__global__ __launch_bounds__(256, 2) void node_gemm_mfma(
    const float* __restrict__ X, const ushort* __restrict__ WnP,
    const ushort* __restrict__ WvP, const ushort* __restrict__ AfqP,
    const ushort* __restrict__ AfkP, const float* __restrict__ bn,
    const float* __restrict__ bv, float* __restrict__ h,
    ushort* __restrict__ vb, ushort* __restrict__ q2p,
    ushort* __restrict__ k2p, int Nn) {
  __shared__ ushort As[128 * 40];
  __shared__ float bS[128];
  const ushort* BP;
  const float* bb = nullptr;
  float* O = nullptr;
  ushort* Ob = nullptr;
  int mode;
  switch (blockIdx.y) {
    case 0: BP = WnP; bb = bn; O = h; mode = 0; break;
    case 1: BP = WvP; bb = bv; Ob = vb; mode = 1; break;
    case 2: BP = AfqP; Ob = q2p; mode = 2; break;
    default: BP = AfkP; Ob = k2p; mode = 2; break;
  }
  const int t = threadIdx.x;
  if (t < 128) bS[t] = bb ? bb[t] : 0.f;
  const int seg = t & 3, arow = t >> 2;  // arow in [0,64)
  const int m0 = blockIdx.x * 128;
  int rIdx[2];
#pragma unroll
  for (int l = 0; l < 2; ++l) rIdx[l] = min(m0 + arow + 64 * l, Nn - 1);
  uint4 avA[2];
#pragma unroll
  for (int l = 0; l < 2; ++l)
    avA[l] = cvt8(X + (size_t)rIdx[l] * 128 + seg * 8);
  f32x4 acc[2][8];
#pragma unroll
  for (int mt = 0; mt < 2; ++mt)
#pragma unroll
    for (int nt = 0; nt < 8; ++nt) acc[mt][nt] = (f32x4)(0.f);
  const int lane = t & 63, wv = t >> 6, l15 = lane & 15, quad = lane >> 4;
  for (int ch = 0; ch < 4; ++ch) {
#pragma unroll
    for (int l = 0; l < 2; ++l)
      *(uint4*)&As[(arow + 64 * l) * 40 + seg * 8] = avA[l];
    __syncthreads();
    if (ch < 3) {
      int o = (ch + 1) * 32 + seg * 8;
#pragma unroll
      for (int l = 0; l < 2; ++l)
        avA[l] = cvt8(X + (size_t)rIdx[l] * 128 + o);
    }
    bf16x8 af[2];
#pragma unroll
    for (int mt = 0; mt < 2; ++mt)
      af[mt] = *(const bf16x8*)&As[(wv * 32 + mt * 16 + l15) * 40 + quad * 8];
    // B fragments straight from global (fragment-ordered, L2-resident):
    const ushort* bp = BP + ((size_t)(ch * 8) * 64 + lane) * 8;
#pragma unroll
    for (int nt = 0; nt < 8; ++nt) {
      bf16x8 bfr = *(const bf16x8*)(bp + nt * 512);
#pragma unroll
      for (int mt = 0; mt < 2; ++mt)
        acc[mt][nt] =
            __builtin_amdgcn_mfma_f32_16x16x32_bf16(af[mt], bfr, acc[mt][nt], 0, 0, 0);
    }
    __syncthreads();
  }
#pragma unroll
  for (int mt = 0; mt < 2; ++mt) {
    int rowb = m0 + wv * 32 + mt * 16 + quad * 4;
#pragma unroll
    for (int nt = 0; nt < 8; ++nt) {
      int col = nt * 16 + l15;
      float b = bS[col];
#pragma unroll
      for (int r = 0; r < 4; ++r) {
        int rg = rowb + r;
        if (rg < Nn) {
          if (mode == 0)      O[(size_t)rg * 128 + col] = acc[mt][nt][r] + b;
          else if (mode == 1) Ob[(size_t)rg * 128 + col] = f2bf(acc[mt][nt][r] + b);
          else                Ob[(size_t)rg * 128 + l15 * 8 + nt] = f2bf(acc[mt][nt][r]);
        }
      }
    }
  }
}

// ---------------------------------------------------------------------------
// K2: streaming edge pipeline, 128 edges/block (M=32/wave), fused CSR-fill
// (atomic-free: slot = offs[src] + rank[e]) and per-block softmax partial.
// THIS ROUND: Bs LDS staging DELETED -- B (Afe) is read directly from global
// in MFMA-fragment order (AfeP, 16KB, L2-resident; same pattern that worked
// in node_gemm). A2s compacted to transposed [8][128] (conflict-free, -512B).
// LDS 27.6KB -> ~16.5KB: LDS cap 5 -> 9 blocks/CU; binding cap becomes
// VGPR (84 -> 6 waves/SIMD = 24 waves = 75%).
// Occupancy/regalloc history: (256,3) VGPR=84 no spill KNOWN GOOD;
//   (256,4) -> VGPR 64 + spills; (256,5) -> VGPR 48 + massive spills.
// Rule: allocator rounds to HW occupancy tiers; min_waves>3 forces a tier
// below the natural ~84 VGPRs and spills. DO NOT TOUCH the (256,3).
__global__ __launch_bounds__(256, 3) void edge_fused4(
    const float* __restrict__ EF, const ushort* __restrict__ AfeP,
    const float* __restrict__ bfold, const float* __restrict__ A2,
    const float* __restrict__ b2, const ushort* __restrict__ q2p,
    const ushort* __restrict__ k2p, const int* __restrict__ src,
    const int* __restrict__ tgt, const int* __restrict__ offs,
    const int* __restrict__ rank,
    int2* __restrict__ cwt, float2* __restrict__ part, int E) {
  __shared__ ushort As[128 * 40];
  __shared__ float A2s[8 * 128];  // transposed: A2s[h][d]
  __shared__ float bfS[128];
  __shared__ float b2s[8];
  __shared__ int sIdxS[128], sIdxT[128], sRank[128];
  __shared__ float redM[16], redS[16];
  const int t = threadIdx.x;
  const int e0 = blockIdx.x * 128;
  if (t < 128) {
    int ec = min(e0 + t, E - 1);
    sIdxS[t] = src[ec];
    sRank[t] = rank[ec];
    bfS[t] = bfold[t];
  } else {
    sIdxT[t - 128] = tgt[min(e0 + t - 128, E - 1)];
  }
  if (t < 8) b2s[t] = b2[t];
#pragma unroll
  for (int l = 0; l < 4; ++l) {
    int i = t + l * 256;  // A2 linear: d = i>>3, h = i&7
    A2s[(i & 7) * 128 + (i >> 3)] = A2[i];
  }
  const int seg = t & 3, arow = t >> 2;  // arow in [0,64)
  int ecl[2];
#pragma unroll
  for (int l = 0; l < 2; ++l) ecl[l] = min(e0 + arow + 64 * l, E - 1);
  uint4 avA[2];
#pragma unroll
  for (int l = 0; l < 2; ++l)
    avA[l] = cvt8(EF + (size_t)ecl[l] * 64 + seg * 8);
  f32x4 acc[2][8];
#pragma unroll
  for (int mt = 0; mt < 2; ++mt)
#pragma unroll
    for (int nt = 0; nt < 8; ++nt) acc[mt][nt] = (f32x4)(0.f);
  const int lane = t & 63, wv = t >> 6, l15 = lane & 15, quad = lane >> 4;

#pragma unroll
  for (int ch = 0; ch < 2; ++ch) {
#pragma unroll
    for (int l = 0; l < 2; ++l)
      *(uint4*)&As[(arow + 64 * l) * 40 + seg * 8] = avA[l];
    __syncthreads();
    if (ch == 0) {
      int o = 32 + seg * 8;
#pragma unroll
      for (int l = 0; l < 2; ++l)
        avA[l] = cvt8(EF + (size_t)ecl[l] * 64 + o);
    }
    bf16x8 af[2];
#pragma unroll
    for (int mt = 0; mt < 2; ++mt)
      af[mt] = *(const bf16x8*)&As[(wv * 32 + mt * 16 + l15) * 40 + quad * 8];
    // B fragments straight from global (fragment-ordered, L2-resident 16KB):
    const ushort* bp = AfeP + ((size_t)(ch * 8) * 64 + lane) * 8;
#pragma unroll
    for (int nt = 0; nt < 8; ++nt) {
      bf16x8 bfr = *(const bf16x8*)(bp + nt * 512);
#pragma unroll
      for (int mt = 0; mt < 2; ++mt)
        acc[mt][nt] =
            __builtin_amdgcn_mfma_f32_16x16x32_bf16(af[mt], bfr, acc[mt][nt], 0, 0, 0);
    }
    if (ch == 0) __syncthreads();
  }

  // epilogue: gather q2/k2 (indices from LDS), bias + lrelu
  float bfv[8];
#pragma unroll
  for (int nt = 0; nt < 8; ++nt) bfv[nt] = bfS[nt * 16 + l15];
#pragma unroll
  for (int mt = 0; mt < 2; ++mt) {
#pragma unroll
    for (int r = 0; r < 4; ++r) {
      int erow = wv * 32 + mt * 16 + quad * 4 + r;
      int si = sIdxS[erow], ti = sIdxT[erow];
      uint4 qv = *(const uint4*)(q2p + (size_t)si * 128 + l15 * 8);
      uint4 kv = *(const uint4*)(k2p + (size_t)ti * 128 + l15 * 8);
      const ushort* qs = (const ushort*)&qv;
      const ushort* ks = (const ushort*)&kv;
#pragma unroll
      for (int nt = 0; nt < 8; ++nt)
        acc[mt][nt][r] =
            lrelu(acc[mt][nt][r] + bf2f(qs[nt]) + bf2f(ks[nt]) + bfv[nt]);
    }
  }
  // head stage: s = mean_h lrelu(hmid @ A2 + b2)
  float tacc[2][4];
#pragma unroll
  for (int mt = 0; mt < 2; ++mt)
#pragma unroll
    for (int r = 0; r < 4; ++r) tacc[mt][r] = 0.f;
  for (int hh = 0; hh < 8; ++hh) {
    float a2v[8];
#pragma unroll
    for (int nt = 0; nt < 8; ++nt) a2v[nt] = A2s[hh * 128 + nt * 16 + l15];
    float b2h = b2s[hh];
#pragma unroll
    for (int mt = 0; mt < 2; ++mt)
#pragma unroll
      for (int r = 0; r < 4; ++r) {
        float p = 0.f;
#pragma unroll
        for (int nt = 0; nt < 8; ++nt) p += acc[mt][nt][r] * a2v[nt];
        p += __shfl_xor(p, 1);
        p += __shfl_xor(p, 2);
        p += __shfl_xor(p, 4);
        p += __shfl_xor(p, 8);
        tacc[mt][r] += lrelu(p + b2h);
      }
  }
  // l15==0 lanes: 8 scores each -> CSR fill (atomic-free) + softmax partial
  if (l15 == 0) {
    float sc[8];
    float m = -1e30f;
#pragma unroll
    for (int mt = 0; mt < 2; ++mt)
#pragma unroll
      for (int r = 0; r < 4; ++r) {
        int i = mt * 4 + r;
        sc[i] = tacc[mt][r] * 0.125f;
        int e = e0 + wv * 32 + mt * 16 + quad * 4 + r;
        if (e < E) m = fmaxf(m, sc[i]);
      }
    float ssum = 0.f;
#pragma unroll
    for (int mt = 0; mt < 2; ++mt)
#pragma unroll
      for (int r = 0; r < 4; ++r) {
        int i = mt * 4 + r;
        int erow = wv * 32 + mt * 16 + quad * 4 + r;
        if (e0 + erow < E) {
          ssum += __expf(sc[i] - m);
          int j = offs[sIdxS[erow]] + sRank[erow];
          cwt[j] = make_int2(sIdxT[erow], __float_as_int(sc[i]));
        }
      }
    int rid = wv * 4 + quad;
    redM[rid] = m;
    redS[rid] = ssum;
  }
  __syncthreads();
  if (t == 0) {
    float M = redM[0], S = redS[0];
#pragma unroll
    for (int i = 1; i < 16; ++i) {
      float m2 = redM[i], s2 = redS[i];
      float Mn = fmaxf(M, m2);
      S = S * __expf(M - Mn) + s2 * __expf(m2 - Mn);
      M = Mn;
    }
    part[blockIdx.x] = make_float2(M, S);
  }
}

// ---------------------------------------------------------------------------
// K3: final reduce of per-block partials -> MS[0]=M, MS[1]=1/sum
__global__ __launch_bounds__(256) void softmax_final(
    const float2* __restrict__ part, int nPart, float* __restrict__ MS) {
  __shared__ float mS[256], sS[256];
  int tid = threadIdx.x;
  float m = -1e30f, sum = 0.f;
  for (int i = tid; i < nPart; i += 256) {
    float2 p = part[i];
    float M = fmaxf(m, p.x);
    sum = sum * __expf(m - M) + p.y * __expf(p.x - M);
    m = M;
  }
  mS[tid] = m;
  sS[tid] = sum;
  __syncthreads();
  for (int off = 128; off > 0; off >>= 1) {
    if (tid < off) {
      float m1 = mS[tid], s1 = sS[tid];
      float m2 = mS[tid + off], s2 = sS[tid + off];
      float M = fmaxf(m1, m2);
      mS[tid] = M;
      sS[tid] = s1 * __expf(m1 - M) + s2 * __expf(m2 - M);
    }
    __syncthreads();
  }
  if (tid == 0) {
    MS[0] = mS[0];
    MS[1] = 1.f / sS[0];
  }
}

// ---------------------------------------------------------------------------
// CSR scan (exclusive prefix over deg)
__global__ __launch_bounds__(256) void scan1(const int* __restrict__ deg,
                                             int* __restrict__ incl,
                                             int* __restrict__ bsum, int N) {
  __shared__ int sh[256];
  int tid = threadIdx.x;
  int i = blockIdx.x * 256 + tid;
  sh[tid] = (i < N) ? deg[i] : 0;
  __syncthreads();
  for (int off = 1; off < 256; off <<= 1) {
    int tv = (tid >= off) ? sh[tid - off] : 0;
    __syncthreads();
    sh[tid] += tv;
    __syncthreads();
  }
  if (i < N) incl[i] = sh[tid];
  if (tid == 255) bsum[blockIdx.x] = sh[255];
}

__global__ __launch_bounds__(256) void scan2(int* __restrict__ bsum, int nb) {
  __shared__ int sh[256];
  int tid = threadIdx.x;
  sh[tid] = (tid < nb) ? bsum[tid] : 0;
  __syncthreads();
  for (int off = 1; off < 256; off <<= 1) {
    int tv = (tid >= off) ? sh[tid - off] : 0;
    __syncthreads();
    sh[tid] += tv;
    __syncthreads();
  }
  if (tid < nb) bsum[tid] = sh[tid];
}

__global__ __launch_bounds__(256) void scan3(const int* __restrict__ deg,
                                             const int* __restrict__ incl,
                                             const int* __restrict__ bsum,
                                             int* __restrict__ offs, int N,
                                             int E) {
  int i = blockIdx.x * 256 + threadIdx.x;
  if (i >= N) return;
  int base = (blockIdx.x > 0) ? bsum[blockIdx.x - 1] : 0;
  int ex = incl[i] - deg[i] + base;
  offs[i] = ex;
  if (i == N - 1) offs[N] = E;
}

// ---------------------------------------------------------------------------
// K5: fused gather (bf16 v) + softmax-normalize + layernorm, unroll x4.
__global__ __launch_bounds__(256) void gather_ln(
    const int* __restrict__ offs, const int2* __restrict__ cwt,
    const ushort* __restrict__ vb, const float* __restrict__ MS,
    const float* __restrict__ gamma, const float* __restrict__ beta,
    float* __restrict__ y, int N) {
  int tid = threadIdx.x;
  int n = blockIdx.x * 4 + (tid >> 6);
  if (n >= N) return;  // wave-uniform
  int lane = tid & 63;
  float M = MS[0], inv = MS[1];
  int beg = offs[n], end = offs[n + 1];
  float a0 = 0.f, a1 = 0.f;
  int j = beg;
  for (; j + 4 <= end; j += 4) {
    int2 p0 = cwt[j], p1 = cwt[j + 1], p2 = cwt[j + 2], p3 = cwt[j + 3];
    unsigned u0 = *(const unsigned*)(vb + (size_t)p0.x * 128 + lane * 2);
    unsigned u1 = *(const unsigned*)(vb + (size_t)p1.x * 128 + lane * 2);
    unsigned u2 = *(const unsigned*)(vb + (size_t)p2.x * 128 + lane * 2);
    unsigned u3 = *(const unsigned*)(vb + (size_t)p3.x * 128 + lane * 2);
    float w0 = __expf(__int_as_float(p0.y) - M) * inv;
    float w1 = __expf(__int_as_float(p1.y) - M) * inv;
    float w2 = __expf(__int_as_float(p2.y) - M) * inv;
    float w3 = __expf(__int_as_float(p3.y) - M) * inv;
    a0 += w0 * bf2f(u0 & 0xffffu) + w1 * bf2f(u1 & 0xffffu) +
          w2 * bf2f(u2 & 0xffffu) + w3 * bf2f(u3 & 0xffffu);
    a1 += w0 * bf2f(u0 >> 16) + w1 * bf2f(u1 >> 16) + w2 * bf2f(u2 >> 16) +
          w3 * bf2f(u3 >> 16);
  }
  for (; j < end; ++j) {
    int2 p = cwt[j];
    float w = __expf(__int_as_float(p.y) - M) * inv;
    unsigned u = *(const unsigned*)(vb + (size_t)p.x * 128 + lane * 2);
    a0 += w * bf2f(u & 0xffffu);
    a1 += w * bf2f(u >> 16);
  }
  size_t base = (size_t)n * 128 + lane * 2;
  float2 hv = *(const float2*)(y + base);
  float y0 = hv.x + a0, y1 = hv.y + a1;
  float sum = y0 + y1, ssq = y0 * y0 + y1 * y1;
#pragma unroll
  for (int off = 1; off < 64; off <<= 1) {
    sum += __shfl_xor(sum, off);
    ssq += __shfl_xor(ssq, off);
  }
  float mu = sum * (1.f / 128.f);
  float var = ssq * (1.f / 128.f) - mu * mu;
  float rstd = rsqrtf(var + EPS);
  float2 g = *(const float2*)(gamma + lane * 2);
  float2 bt = *(const float2*)(beta + lane * 2);
  float2 out;
  out.x = g.x * (y0 - mu) * rstd + bt.x;
  out.y = g.y * (y1 - mu) * rstd + bt.y;
  *(float2*)(y + base) = out;
}

// ---------------------------------------------------------------------------
extern "C" void kernel_launch(void* const* d_in, const int* in_sizes, int n_in,
                              void* d_out, int out_size, void* d_ws,
                              size_t ws_size, hipStream_t stream) {
  const float* X  = (const float*)d_in[0];
  const float* EF = (const float*)d_in[1];
  const float* Wn = (const float*)d_in[2];
  const float* bn = (const float*)d_in[3];
  const float* Wq = (const float*)d_in[4];
  const float* bq = (const float*)d_in[5];
  const float* Wk = (const float*)d_in[6];
  const float* bk = (const float*)d_in[7];
  const float* Wv = (const float*)d_in[8];
  const float* bv = (const float*)d_in[9];
  const float* We = (const float*)d_in[10];
  const float* be = (const float*)d_in[11];
  const float* A1 = (const float*)d_in[12];
  const float* b1 = (const float*)d_in[13];
  const float* A2 = (const float*)d_in[14];
  const float* b2 = (const float*)d_in[15];
  const float* gamma = (const float*)d_in[16];
  const float* beta  = (const float*)d_in[17];
  const int* ei = (const int*)d_in[18];

  int N = in_sizes[0] / D;   // 50000
  int E = in_sizes[1] / DE;  // 400000
  const int* src = ei;
  const int* tgt = ei + E;

  float* h = (float*)d_out;  // h accumulated/normalized in place
  float* ws = (float*)d_ws;
  float2* part = (float2*)ws;                          // 4096 cap
  float* MS    = (float*)(part + 4096);                // 4
  float* bfold = MS + 4;                               // 128
  ushort* vb   = (ushort*)(bfold + 128);               // N*128 bf16
  ushort* q2p  = vb + (size_t)N * D;                   // N*128
  ushort* k2p  = q2p + (size_t)N * D;                  // N*128
  ushort* AfqP = k2p + (size_t)N * D;                  // 128*128
  ushort* AfkP = AfqP + 128 * 128;                     // 128*128
  ushort* AfeP = AfkP + 128 * 128;                     // 128*64
  ushort* WnP  = AfeP + 128 * 64;                      // 128*128
  ushort* WvP  = WnP + 128 * 128;                      // 128*128
  int* deg    = (int*)(WvP + 128 * 128);               // N
  int* incl   = deg + N;                               // N
  int* bsum   = incl + N;                              // 256
  int* rank   = bsum + 256;                            // E
  int* offs   = rank + E;                              // N+2
  int2* cwt   = (int2*)(offs + N + 2);                 // E

  int nbScan = (N + 255) / 256;          // 196 (<= 256)
  int nbEdge = (E + 127) / 128;          // 3125 (<= 4096 part cap)
  int nbHist = (E + 127) / 128;

  hipMemsetAsync(deg, 0, (size_t)N * sizeof(int), stream);
  fold_pack<<<577 + nbHist, 128, 0, stream>>>(Wq, Wk, We, A1, bq, bk, be, b1,
                                              Wn, Wv, AfqP, AfkP, AfeP, bfold,
                                              WnP, WvP, src, deg, rank, E);
  scan1<<<nbScan, 256, 0, stream>>>(deg, incl, bsum, N);
  scan2<<<1, 256, 0, stream>>>(bsum, nbScan);
  scan3<<<nbScan, 256, 0, stream>>>(deg, incl, bsum, offs, N, E);
  node_gemm_mfma<<<dim3((N + 127) / 128, 4), 256, 0, stream>>>(
      X, WnP, WvP, AfqP, AfkP, bn, bv, h, vb, q2p, k2p, N);
  edge_fused4<<<nbEdge, 256, 0, stream>>>(EF, AfeP, bfold, A2, b2, q2p, k2p,
                                          src, tgt, offs, rank, cwt, part, E);
  softmax_final<<<1, 256, 0, stream>>>(part, nbEdge, MS);
  gather_ln<<<(N + 3) / 4, 256, 0, stream>>>(offs, cwt, vb, MS, gamma, beta, h,
                                             N);
}